// Round 1
// baseline (205.608 us; speedup 1.0000x reference)
//
#include <hip/hip_runtime.h>
#include <hip/hip_bf16.h>
#include <hip/hip_fp8.h>
#include <stdint.h>

typedef float floatx4 __attribute__((ext_vector_type(4)));

#define B_    4096
#define D_    1024
#define C_    1000
#define CPAD  1024
#define NVALID (B_ + C_)    // 5096 valid columns
#define TAU_INV 10.0f
#define EPS_    1e-8f

__device__ inline unsigned cvt4_fp8(float4 v) {
    __hip_fp8_e4m3 a(v.x), b(v.y), c(v.z), d(v.w);
    return (unsigned)a.__x | ((unsigned)b.__x << 8) | ((unsigned)c.__x << 16) | ((unsigned)d.__x << 24);
}

// ---------------- prep: cvt fp32->fp8, zero accum + pad, class counts ------
// grid 5111 x 256. Work map (g = global thread):
//   [0, 1048576)         : features cvt, float4 #g -> u32 fp8x4   (4096*1024/4)
//   [1048576, 1304576)   : centers  cvt, float4 #(g-1048576)      (1000*1024/4)
//   [1304576, 1306624)   : zero denom(1024 f4) then possum(1024 f4)
//   [1306624, 1308160)   : zero center pad rows, int4 (24*1024 B = 1536 int4)
// block 5110 computes counts[1024] via LDS atomics and zeroes the ticket.
__global__ __launch_bounds__(256) void prep_kernel(
    const float* __restrict__ centers, const float* __restrict__ features,
    const int* __restrict__ targets,
    unsigned* __restrict__ Af8, unsigned* __restrict__ Cf8,
    float* __restrict__ denom, float* __restrict__ possum, int* __restrict__ counts,
    int* __restrict__ ticket)
{
    const int tid = threadIdx.x;
    const int g = blockIdx.x * 256 + tid;
    if (g < 1048576) {
        Af8[g] = cvt4_fp8(((const float4*)features)[g]);
    } else if (g < 1304576) {
        int i = g - 1048576;
        Cf8[i] = cvt4_fp8(((const float4*)centers)[i]);
    } else if (g < 1306624) {
        int i = g - 1304576;                    // 0..2047
        float4 z = make_float4(0.f, 0.f, 0.f, 0.f);
        if (i < 1024) ((float4*)denom)[i] = z;
        else          ((float4*)possum)[i - 1024] = z;
    } else if (g < 1308160) {
        int i = g - 1306624;                    // 0..1535
        int4 z = make_int4(0, 0, 0, 0);
        ((int4*)((uint8_t*)Cf8 + (size_t)C_ * D_))[i] = z;
    }
    if (blockIdx.x == 5110) {
        __shared__ int lc[CPAD];
        if (tid == 0) ticket[0] = 0;
        #pragma unroll
        for (int j = 0; j < 4; ++j) lc[tid * 4 + j] = 0;
        __syncthreads();
        for (int i = tid; i < B_; i += 256) atomicAdd(&lc[targets[i]], 1);
        __syncthreads();
        int4 o; o.x = lc[tid*4]; o.y = lc[tid*4+1]; o.z = lc[tid*4+2]; o.w = lc[tid*4+3];
        ((int4*)counts)[tid] = o;
    }
}

// ---------------- fused symmetric fp8 GEMM + dual-sided epilogue ------------
// Tiles: bid < 528  -> symmetric F.F^T pair (rt <= ct), mirror if rt != ct
//        bid >= 528 -> center tiles: rt = m>>3, col block m&7 of Cf8
// BK = 64 (fp8): DOUBLE-BUFFERED LDS (2x 8 KiB per matrix = 32 KiB total).
// 2-phase schedule: STAGE(next tile, other buffer) is issued BEFORE the MFMA
// burst on the current buffer; the single __syncthreads() per K-step (which
// drains vmcnt) then lands after ~250cy of compute, hiding the L2 latency of
// the staging loads. This replaces the old load->barrier->compute->barrier
// structure (zero overlap, 2 drains/K-step).
// LDS layout XOR-swizzled on 16-B chunks (applied on the GLOBAL fetch side so
// global_load_lds's contiguous 1024-B wave-write is preserved).
// Finalize is fused via a device-scope ticket: the last block to finish
// computes the scalar loss (saves a launch + serialized 1-block dispatch).
#define GLD_LDS16(g, l) __builtin_amdgcn_global_load_lds( \
    (const __attribute__((address_space(1))) void*)(g),   \
    (__attribute__((address_space(3))) void*)(l), 16, 0, 0)

__global__ __launch_bounds__(256, 4) void gemm_fused(
    const uint8_t* __restrict__ Af8,   // [4096][1024] fp8 e4m3
    const uint8_t* __restrict__ Cf8,   // [1024][1024] fp8 (rows >= 1000 zero)
    const int*     __restrict__ counts,
    const int*     __restrict__ targets,
    float* __restrict__ denom, float* __restrict__ possum,
    int* __restrict__ ticket, float* __restrict__ out)
{
    __shared__ __align__(16) uint8_t ldsA[2][128 * 64];
    __shared__ __align__(16) uint8_t ldsB[2][128 * 64];
    __shared__ int   lastflag;
    __shared__ float red[4];

    const int tid  = threadIdx.x;
    const int wave = tid >> 6;
    const int lane = tid & 63;
    // XCD-contiguous bijective swizzle: 784 = 8 * 98, xcd = blockIdx.x % 8
    // (round-robin dispatch) gets a contiguous run of 98 tiles -> row-strip
    // A-panels and denom[] atomic lines stay in one XCD's L2.
    const int bid0 = blockIdx.x;
    const int bid  = (bid0 & 7) * 98 + (bid0 >> 3);

    int rt, colTile;
    const uint8_t* Bbase;
    bool mirror;
    if (bid < 528) {
        int idx = bid, r = 0;
        while (idx >= 32 - r) { idx -= 32 - r; ++r; }   // scalar, uniform
        rt = r;
        int ct = r + idx;
        colTile = ct * 128;
        Bbase = Af8 + (size_t)ct * 128 * D_;
        mirror = (ct != rt);
    } else {
        int m = bid - 528;
        rt = m >> 3;
        int cc = m & 7;
        colTile = B_ + cc * 128;
        Bbase = Cf8 + (size_t)cc * 128 * D_;
        mirror = false;
    }
    const int rowTile = rt * 128;

    // ---- staging map: 2 instrs per matrix per thread; instr j covers rows
    // (wave + 4j)*16 .. +15 (lane>>2 within), chunk (lane&3) XOR-permuted.
    const int r0 = wave * 16 + (lane >> 2);         // j = 0 local row
    const int r1 = r0 + 64;                          // j = 1 local row
    const int gc0 = ((lane & 3) ^ ((r0 >> 1) & 3)) * 16;
    const int gc1 = ((lane & 3) ^ ((r1 >> 1) & 3)) * 16;
    const uint8_t* gA0 = Af8 + (size_t)(rowTile + r0) * D_ + gc0;
    const uint8_t* gA1 = Af8 + (size_t)(rowTile + r1) * D_ + gc1;
    const uint8_t* gB0 = Bbase + (size_t)r0 * D_ + gc0;
    const uint8_t* gB1 = Bbase + (size_t)r1 * D_ + gc1;
    const int sA = wave * 1024;                      // LDS dest offset (wave-uniform)

    floatx4 acc[4][4] = {};

    const int wrow  = (wave >> 1) * 64;
    const int wcolw = (wave & 1) * 64;
    const int fr = lane & 15;
    const int fq = lane >> 4;
    // fragment LDS byte offsets within a row, per k-step s:
    const int sw = (fr >> 1) & 3;
    const int off_s0 = (((fq >> 1) ^ sw) * 16) + (fq & 1) * 8;          // s=0
    const int off_s1 = (((2 + (fq >> 1)) ^ sw) * 16) + (fq & 1) * 8;    // s=1

#define STAGE(buf, k)                                   \
    do {                                                \
        GLD_LDS16(gA0 + (k), &ldsA[buf][sA]);           \
        GLD_LDS16(gA1 + (k), &ldsA[buf][sA + 4096]);    \
        GLD_LDS16(gB0 + (k), &ldsB[buf][sA]);           \
        GLD_LDS16(gB1 + (k), &ldsB[buf][sA + 4096]);    \
    } while (0)

#define COMPUTE(buf)                                                              \
    do {                                                                          \
        _Pragma("unroll")                                                         \
        for (int s = 0; s < 2; ++s) {                                             \
            const int off = s ? off_s1 : off_s0;                                  \
            long af[4], bfv[4];                                                   \
            _Pragma("unroll")                                                     \
            for (int ri = 0; ri < 4; ++ri)                                        \
                af[ri] = *(const long*)&ldsA[buf][(wrow + ri * 16 + fr) * 64 + off]; \
            _Pragma("unroll")                                                     \
            for (int ci = 0; ci < 4; ++ci)                                        \
                bfv[ci] = *(const long*)&ldsB[buf][(wcolw + ci * 16 + fr) * 64 + off]; \
            _Pragma("unroll")                                                     \
            for (int ri = 0; ri < 4; ++ri) {                                      \
                _Pragma("unroll")                                                 \
                for (int ci = 0; ci < 4; ++ci)                                    \
                    acc[ri][ci] = __builtin_amdgcn_mfma_f32_16x16x32_fp8_fp8(     \
                        af[ri], bfv[ci], acc[ri][ci], 0, 0, 0);                   \
            }                                                                     \
        }                                                                         \
    } while (0)

    // ---- 2-phase double-buffered K-loop: 16 K-tiles, 1 barrier per tile ----
    STAGE(0, 0);
    __syncthreads();                        // drain prologue stage
    for (int tt = 0; tt < 7; ++tt) {
        STAGE(1, tt * 128 + 64);            // prefetch next tile into buf1
        COMPUTE(0);                         // compute current (buf0)
        __syncthreads();                    // drains vmcnt -> buf1 ready
        STAGE(0, tt * 128 + 128);           // prefetch into buf0
        COMPUTE(1);
        __syncthreads();
    }
    STAGE(1, 960);
    COMPUTE(0);                             // k = 896
    __syncthreads();
    COMPUTE(1);                             // k = 960

#undef STAGE
#undef COMPUTE

    // ---- epilogue ----
    float wv[4]; int tcol[4]; int colg[4];
    #pragma unroll
    for (int ci = 0; ci < 4; ++ci) {
        int cg = colTile + wcolw + ci * 16 + fr;
        colg[ci] = cg;
        int cls = (cg < B_) ? targets[cg] : (cg - B_);
        tcol[ci] = cls;
        wv[ci] = (cg < NVALID) ? 1.f / (float)(counts[cls] + 1) : 0.f;
    }

    float dcol[4] = {0.f, 0.f, 0.f, 0.f};
    float pcol[4] = {0.f, 0.f, 0.f, 0.f};

    #pragma unroll
    for (int ri = 0; ri < 4; ++ri) {
        #pragma unroll
        for (int reg = 0; reg < 4; ++reg) {
            int rowg = rowTile + wrow + ri * 16 + fq * 4 + reg;   // C/D: row=(lane>>4)*4+reg
            int trow = targets[rowg];
            float wr = 1.f / (float)(counts[trow] + 1);
            float dsum = 0.f, psum = 0.f;
            #pragma unroll
            for (int ci = 0; ci < 4; ++ci) {
                float s = acc[ri][ci][reg] * TAU_INV;
                float e = __expf(s);
                dsum += wv[ci] * e;
                bool pos = (tcol[ci] == trow) && (colg[ci] != rowg);
                float gterm = pos ? (s + log1pf(EPS_ * __expf(-s))) : 0.f;   // log(exp(s)+eps)
                psum += gterm;
                if (mirror) { dcol[ci] += wr * e; pcol[ci] += gterm; }
            }
            #pragma unroll
            for (int m = 1; m < 16; m <<= 1) {
                dsum += __shfl_xor(dsum, m, 64);
                psum += __shfl_xor(psum, m, 64);
            }
            if (fr == 0) {
                atomicAdd(&denom[rowg],  dsum);
                atomicAdd(&possum[rowg], psum);
            }
        }
    }

    if (mirror) {
        #pragma unroll
        for (int ci = 0; ci < 4; ++ci) {
            float d = dcol[ci], p = pcol[ci];
            d += __shfl_xor(d, 16, 64); d += __shfl_xor(d, 32, 64);
            p += __shfl_xor(p, 16, 64); p += __shfl_xor(p, 32, 64);
            if (fq == 0) {
                atomicAdd(&denom[colg[ci]],  d);
                atomicAdd(&possum[colg[ci]], p);
            }
        }
    }

    // ---- fused finalize: last block to finish computes the scalar loss ----
    __threadfence();                        // each wave: drain + publish its atomics
    __syncthreads();
    if (tid == 0)
        lastflag = (atomicAdd(ticket, 1) == (int)gridDim.x - 1) ? 1 : 0;
    __syncthreads();
    if (lastflag) {
        __threadfence();                    // acquire: invalidate before reading others' adds
        float local = 0.f;
        for (int i = tid; i < B_; i += 256) {
            float npos = (float)counts[targets[i]];
            local += logf(denom[i] + EPS_) - possum[i] / npos;
        }
        #pragma unroll
        for (int m = 1; m < 64; m <<= 1) local += __shfl_xor(local, m, 64);
        if ((tid & 63) == 0) red[tid >> 6] = local;
        __syncthreads();
        if (tid == 0) out[0] = (red[0] + red[1] + red[2] + red[3]) * (1.f / (float)B_);
    }
}

extern "C" void kernel_launch(void* const* d_in, const int* in_sizes, int n_in,
                              void* d_out, int out_size, void* d_ws, size_t ws_size,
                              hipStream_t stream) {
    const float* centers  = (const float*)d_in[0];   // [1000][1024]
    const float* features = (const float*)d_in[1];   // [4096][1024]
    const int*   targets  = (const int*)d_in[2];     // [4096]
    float* out = (float*)d_out;

    char* ws = (char*)d_ws;
    unsigned* Af8   = (unsigned*)(ws);                     // 4 MiB fp8
    unsigned* Cf8   = (unsigned*)(ws + 4194304);           // 1 MiB fp8 (rows 1000..1023 zeroed)
    int*    counts = (int*)   (ws + 5242880);              // 1024 i32
    float*  denom  = (float*) (ws + 5246976);              // 4096 f32
    float*  possum = (float*) (ws + 5263360);              // 4096 f32
    int*    ticket = (int*)   (ws + 5279744);              // 1 i32 (last-block flag)

    hipLaunchKernelGGL(prep_kernel, dim3(5111), dim3(256), 0, stream,
                       centers, features, targets, Af8, Cf8, denom, possum, counts, ticket);
    hipLaunchKernelGGL(gemm_fused, dim3(784), dim3(256), 0, stream,
                       (const uint8_t*)Af8, (const uint8_t*)Cf8, counts, targets,
                       denom, possum, ticket, out);
}

// Round 2
// 149.647 us; speedup vs baseline: 1.3740x; 1.3740x over previous
//
#include <hip/hip_runtime.h>
#include <hip/hip_bf16.h>
#include <hip/hip_fp8.h>
#include <stdint.h>

typedef float floatx4 __attribute__((ext_vector_type(4)));

#define B_    4096
#define D_    1024
#define C_    1000
#define CPAD  1024
#define NVALID (B_ + C_)    // 5096 valid columns
#define TAU_INV 10.0f
#define EPS_    1e-8f

__device__ inline unsigned cvt4_fp8(float4 v) {
    __hip_fp8_e4m3 a(v.x), b(v.y), c(v.z), d(v.w);
    return (unsigned)a.__x | ((unsigned)b.__x << 8) | ((unsigned)c.__x << 16) | ((unsigned)d.__x << 24);
}

// ---------------- prep: cvt fp32->fp8, zero accum + pad, class counts ------
// grid 5111 x 256. Work map (g = global thread):
//   [0, 1048576)         : features cvt, float4 #g -> u32 fp8x4   (4096*1024/4)
//   [1048576, 1304576)   : centers  cvt, float4 #(g-1048576)      (1000*1024/4)
//   [1304576, 1306624)   : zero denom(1024 f4) then possum(1024 f4)
//   [1306624, 1308160)   : zero center pad rows, int4 (24*1024 B = 1536 int4)
// block 5110 (g >= 1308160, idle above) computes counts[1024] via LDS atomics.
__global__ __launch_bounds__(256) void prep_kernel(
    const float* __restrict__ centers, const float* __restrict__ features,
    const int* __restrict__ targets,
    unsigned* __restrict__ Af8, unsigned* __restrict__ Cf8,
    float* __restrict__ denom, float* __restrict__ possum, int* __restrict__ counts)
{
    const int tid = threadIdx.x;
    const int g = blockIdx.x * 256 + tid;
    if (g < 1048576) {
        Af8[g] = cvt4_fp8(((const float4*)features)[g]);
    } else if (g < 1304576) {
        int i = g - 1048576;
        Cf8[i] = cvt4_fp8(((const float4*)centers)[i]);
    } else if (g < 1306624) {
        int i = g - 1304576;                    // 0..2047
        float4 z = make_float4(0.f, 0.f, 0.f, 0.f);
        if (i < 1024) ((float4*)denom)[i] = z;
        else          ((float4*)possum)[i - 1024] = z;
    } else if (g < 1308160) {
        int i = g - 1306624;                    // 0..1535
        int4 z = make_int4(0, 0, 0, 0);
        ((int4*)((uint8_t*)Cf8 + (size_t)C_ * D_))[i] = z;
    }
    if (blockIdx.x == 5110) {
        __shared__ int lc[CPAD];
        #pragma unroll
        for (int j = 0; j < 4; ++j) lc[tid * 4 + j] = 0;
        __syncthreads();
        for (int i = tid; i < B_; i += 256) atomicAdd(&lc[targets[i]], 1);
        __syncthreads();
        int4 o; o.x = lc[tid*4]; o.y = lc[tid*4+1]; o.z = lc[tid*4+2]; o.w = lc[tid*4+3];
        ((int4*)counts)[tid] = o;
    }
}

// ---------------- fused symmetric fp8 GEMM + dual-sided epilogue ------------
// Tiles: bid < 528  -> symmetric F.F^T pair (rt <= ct), mirror if rt != ct
//        bid >= 528 -> center tiles: rt = m>>3, col block m&7 of Cf8
// BK = 64 (fp8). 2-phase double-buffer, with the two buffers as FOUR SEPARATE
// __shared__ objects (ldsA0/ldsA1/ldsB0/ldsB1). This is the round-1 fix:
// with ldsA[2][...] as one array, LLVM's LDS-DMA waitcnt tracking could not
// disambiguate the in-flight global_load_lds (buf1) from the ds_reads (buf0)
// and inserted s_waitcnt vmcnt(0) BEFORE the MFMA burst, serializing every
// K-step (68us -> 128us). Distinct objects give provable NoAlias, so the only
// vmcnt drain is at the per-step __syncthreads(), which lands after the
// compute phase: per-step stall = max(0, L_stage - T_compute).
// LDS layout XOR-swizzled on 16-B chunks (applied on the GLOBAL fetch side so
// global_load_lds's contiguous 1024-B wave-write is preserved).
#define GLD_LDS16(g, l) __builtin_amdgcn_global_load_lds( \
    (const __attribute__((address_space(1))) void*)(g),   \
    (__attribute__((address_space(3))) void*)(l), 16, 0, 0)

__global__ __launch_bounds__(256, 4) void gemm_epilogue(
    const uint8_t* __restrict__ Af8,   // [4096][1024] fp8 e4m3
    const uint8_t* __restrict__ Cf8,   // [1024][1024] fp8 (rows >= 1000 zero)
    const int*     __restrict__ counts,
    const int*     __restrict__ targets,
    float* __restrict__ denom, float* __restrict__ possum)
{
    __shared__ __align__(16) uint8_t ldsA0[128 * 64];
    __shared__ __align__(16) uint8_t ldsA1[128 * 64];
    __shared__ __align__(16) uint8_t ldsB0[128 * 64];
    __shared__ __align__(16) uint8_t ldsB1[128 * 64];

    const int tid  = threadIdx.x;
    const int wave = tid >> 6;
    const int lane = tid & 63;
    const int bid  = blockIdx.x;

    int rt, colTile;
    const uint8_t* Bbase;
    bool mirror;
    if (bid < 528) {
        int idx = bid, r = 0;
        while (idx >= 32 - r) { idx -= 32 - r; ++r; }   // scalar, uniform
        rt = r;
        int ct = r + idx;
        colTile = ct * 128;
        Bbase = Af8 + (size_t)ct * 128 * D_;
        mirror = (ct != rt);
    } else {
        int m = bid - 528;
        rt = m >> 3;
        int cc = m & 7;
        colTile = B_ + cc * 128;
        Bbase = Cf8 + (size_t)cc * 128 * D_;
        mirror = false;
    }
    const int rowTile = rt * 128;

    // ---- staging map: 2 instrs per matrix per thread; instr j covers rows
    // (wave + 4j)*16 .. +15 (lane>>2 within), chunk (lane&3) XOR-permuted.
    const int r0 = wave * 16 + (lane >> 2);         // j = 0 local row
    const int r1 = r0 + 64;                          // j = 1 local row
    const int gc0 = ((lane & 3) ^ ((r0 >> 1) & 3)) * 16;
    const int gc1 = ((lane & 3) ^ ((r1 >> 1) & 3)) * 16;
    const uint8_t* gA0 = Af8 + (size_t)(rowTile + r0) * D_ + gc0;
    const uint8_t* gA1 = Af8 + (size_t)(rowTile + r1) * D_ + gc1;
    const uint8_t* gB0 = Bbase + (size_t)r0 * D_ + gc0;
    const uint8_t* gB1 = Bbase + (size_t)r1 * D_ + gc1;
    const int sA = wave * 1024;                      // LDS dest offset (wave-uniform)

    floatx4 acc[4][4] = {};

    const int wrow  = (wave >> 1) * 64;
    const int wcolw = (wave & 1) * 64;
    const int fr = lane & 15;
    const int fq = lane >> 4;
    // fragment LDS byte offsets within a row, per k-step s:
    const int sw = (fr >> 1) & 3;
    const int off_s0 = (((fq >> 1) ^ sw) * 16) + (fq & 1) * 8;          // s=0
    const int off_s1 = (((2 + (fq >> 1)) ^ sw) * 16) + (fq & 1) * 8;    // s=1

#define STAGE(bs, k)                                  \
    do {                                              \
        GLD_LDS16(gA0 + (k), &ldsA##bs[sA]);          \
        GLD_LDS16(gA1 + (k), &ldsA##bs[sA + 4096]);   \
        GLD_LDS16(gB0 + (k), &ldsB##bs[sA]);          \
        GLD_LDS16(gB1 + (k), &ldsB##bs[sA + 4096]);   \
    } while (0)

#define COMPUTE(bs)                                                               \
    do {                                                                          \
        _Pragma("unroll")                                                         \
        for (int s = 0; s < 2; ++s) {                                             \
            const int off = s ? off_s1 : off_s0;                                  \
            long af[4], bfv[4];                                                   \
            _Pragma("unroll")                                                     \
            for (int ri = 0; ri < 4; ++ri)                                        \
                af[ri] = *(const long*)&ldsA##bs[(wrow + ri * 16 + fr) * 64 + off]; \
            _Pragma("unroll")                                                     \
            for (int ci = 0; ci < 4; ++ci)                                        \
                bfv[ci] = *(const long*)&ldsB##bs[(wcolw + ci * 16 + fr) * 64 + off]; \
            _Pragma("unroll")                                                     \
            for (int ri = 0; ri < 4; ++ri) {                                      \
                _Pragma("unroll")                                                 \
                for (int ci = 0; ci < 4; ++ci)                                    \
                    acc[ri][ci] = __builtin_amdgcn_mfma_f32_16x16x32_fp8_fp8(     \
                        af[ri], bfv[ci], acc[ri][ci], 0, 0, 0);                   \
            }                                                                     \
        }                                                                         \
    } while (0)

    // ---- 2-phase double-buffered K-loop: 16 K-tiles, 1 barrier per tile ----
    STAGE(0, 0);
    __syncthreads();                        // drain prologue stage
    for (int tt = 0; tt < 7; ++tt) {
        STAGE(1, tt * 128 + 64);            // prefetch next tile into buf1
        COMPUTE(0);                         // compute current (buf0)
        __syncthreads();                    // drains vmcnt -> buf1 ready
        STAGE(0, tt * 128 + 128);           // prefetch into buf0
        COMPUTE(1);
        __syncthreads();
    }
    STAGE(1, 960);
    COMPUTE(0);                             // k = 896
    __syncthreads();
    COMPUTE(1);                             // k = 960

#undef STAGE
#undef COMPUTE

    // ---- epilogue ----
    float wv[4]; int tcol[4]; int colg[4];
    #pragma unroll
    for (int ci = 0; ci < 4; ++ci) {
        int cg = colTile + wcolw + ci * 16 + fr;
        colg[ci] = cg;
        int cls = (cg < B_) ? targets[cg] : (cg - B_);
        tcol[ci] = cls;
        wv[ci] = (cg < NVALID) ? 1.f / (float)(counts[cls] + 1) : 0.f;
    }

    float dcol[4] = {0.f, 0.f, 0.f, 0.f};
    float pcol[4] = {0.f, 0.f, 0.f, 0.f};

    #pragma unroll
    for (int ri = 0; ri < 4; ++ri) {
        #pragma unroll
        for (int reg = 0; reg < 4; ++reg) {
            int rowg = rowTile + wrow + ri * 16 + fq * 4 + reg;   // C/D: row=(lane>>4)*4+reg
            int trow = targets[rowg];
            float wr = 1.f / (float)(counts[trow] + 1);
            float dsum = 0.f, psum = 0.f;
            #pragma unroll
            for (int ci = 0; ci < 4; ++ci) {
                float s = acc[ri][ci][reg] * TAU_INV;
                float e = __expf(s);
                dsum += wv[ci] * e;
                bool pos = (tcol[ci] == trow) && (colg[ci] != rowg);
                float gterm = pos ? (s + log1pf(EPS_ * __expf(-s))) : 0.f;   // log(exp(s)+eps)
                psum += gterm;
                if (mirror) { dcol[ci] += wr * e; pcol[ci] += gterm; }
            }
            #pragma unroll
            for (int m = 1; m < 16; m <<= 1) {
                dsum += __shfl_xor(dsum, m, 64);
                psum += __shfl_xor(psum, m, 64);
            }
            if (fr == 0) {
                atomicAdd(&denom[rowg],  dsum);
                atomicAdd(&possum[rowg], psum);
            }
        }
    }

    if (mirror) {
        #pragma unroll
        for (int ci = 0; ci < 4; ++ci) {
            float d = dcol[ci], p = pcol[ci];
            d += __shfl_xor(d, 16, 64); d += __shfl_xor(d, 32, 64);
            p += __shfl_xor(p, 16, 64); p += __shfl_xor(p, 32, 64);
            if (fq == 0) {
                atomicAdd(&denom[colg[ci]],  d);
                atomicAdd(&possum[colg[ci]], p);
            }
        }
    }
}

// ---------------- finalize: per-sample loss -> mean -------------------------
__global__ void finalize_kernel(const float* __restrict__ denom, const float* __restrict__ possum,
                                const int* __restrict__ counts, const int* __restrict__ targets,
                                float* __restrict__ out) {
    __shared__ float red[4];
    float local = 0.f;
    for (int i = threadIdx.x; i < B_; i += 256) {
        float npos = (float)counts[targets[i]];
        local += logf(denom[i] + EPS_) - possum[i] / npos;
    }
    #pragma unroll
    for (int m = 1; m < 64; m <<= 1) local += __shfl_xor(local, m, 64);
    int w = threadIdx.x >> 6;
    if ((threadIdx.x & 63) == 0) red[w] = local;
    __syncthreads();
    if (threadIdx.x == 0) out[0] = (red[0] + red[1] + red[2] + red[3]) * (1.f / (float)B_);
}

extern "C" void kernel_launch(void* const* d_in, const int* in_sizes, int n_in,
                              void* d_out, int out_size, void* d_ws, size_t ws_size,
                              hipStream_t stream) {
    const float* centers  = (const float*)d_in[0];   // [1000][1024]
    const float* features = (const float*)d_in[1];   // [4096][1024]
    const int*   targets  = (const int*)d_in[2];     // [4096]
    float* out = (float*)d_out;

    char* ws = (char*)d_ws;
    unsigned* Af8   = (unsigned*)(ws);                     // 4 MiB fp8
    unsigned* Cf8   = (unsigned*)(ws + 4194304);           // 1 MiB fp8 (rows 1000..1023 zeroed)
    int*    counts = (int*)   (ws + 5242880);              // 1024 i32
    float*  denom  = (float*) (ws + 5246976);              // 4096 f32
    float*  possum = (float*) (ws + 5263360);              // 4096 f32

    hipLaunchKernelGGL(prep_kernel, dim3(5111), dim3(256), 0, stream,
                       centers, features, targets, Af8, Cf8, denom, possum, counts);
    hipLaunchKernelGGL(gemm_epilogue, dim3(784), dim3(256), 0, stream,
                       (const uint8_t*)Af8, (const uint8_t*)Cf8, counts, targets, denom, possum);
    hipLaunchKernelGGL(finalize_kernel, dim3(1), dim3(256), 0, stream,
                       denom, possum, counts, targets, out);
}